// Round 11
// baseline (478.003 us; speedup 1.0000x reference)
//
#include <hip/hip_runtime.h>

#define CRF_B 1024
#define CRF_T 512
#define CRF_K 64
#define CRF_START 62
#define CRF_STOP 63

typedef float vf16 __attribute__((ext_vector_type(16)));

__device__ __forceinline__ float wave_sum64(float v) {
#pragma unroll
  for (int off = 32; off > 0; off >>= 1) v += __shfl_xor(v, off, 64);
  return v;
}

// R6 (third resubmit, unmeasured due to GPU acquisition timeouts):
// broadcast via ds_bpermute instead of v_readlane. Post-mortem model (fits
// R0/R3/R4/R5): per-step time ~ 8cy * readlane_count -> v_readlane
// throughput (~8cy, VGPR->SGPR path) is the wall; scheduling changes around
// it were neutral. ds_bpermute with a uniform index is a VGPR->VGPR
// broadcast on the DS pipe (m255: within 1.2x of permlane; m134: ~6cy
// b32-class), and DS issue overlaps the VALU FMA stream. Also reverts E
// access to R3's direct-constant-extract pattern: R5's Eget ternary lambda
// demoted E to scratch (VGPR_Count=48 vs R3's 128).
__global__ __launch_bounds__(128, 1) void crf_kernel(
    const float* __restrict__ feats, const int* __restrict__ lengths,
    const int* __restrict__ tags, const float* __restrict__ trans,
    float* __restrict__ out) {
  // padded stride 65: conflict-free row reads, cheap random reads for gold wave
  __shared__ float sT[CRF_K * 65];

  const int b = blockIdx.x;
  const int tid = threadIdx.x;
  const int lane = tid & 63;

  for (int idx = tid; idx < CRF_K * CRF_K; idx += 128)
    sT[(idx >> 6) * 65 + (idx & 63)] = trans[idx];
  __syncthreads();

  const int L = lengths[b];

  if (tid < 64) {
    // ---------------- forward wave (exp domain) ----------------
    // Opaque zero in a VGPR: the bpermute index becomes (zosrc + 4*j), which
    // the compiler folds into the DS offset: field (one shared addr VGPR, no
    // per-use v_mov), and cannot constant-fold away.
    int zosrc = 0;
    asm volatile("" : "+v"(zosrc));

    // lane i holds E row i = exp(trans[i][0..63]) in four ext-vector SSA
    // values; constant-index extracts only (R3-proven VGPR-resident pattern).
    vf16 E0, E1, E2, E3;
    {
      const float* trow = &sT[lane * 65];
#pragma unroll
      for (int j = 0; j < 16; ++j) E0[j] = __expf(trow[j]);
#pragma unroll
      for (int j = 0; j < 16; ++j) E1[j] = __expf(trow[16 + j]);
#pragma unroll
      for (int j = 0; j < 16; ++j) E2[j] = __expf(trow[32 + j]);
#pragma unroll
      for (int j = 0; j < 16; ++j) E3[j] = __expf(trow[48 + j]);
    }

    const float* bfeats = feats + (size_t)b * CRF_T * CRF_K + lane;

    // P[i] = exp(alpha[i] - offset); alpha0 = delta_START
    float P = (lane == CRF_START) ? 1.0f : 0.0f;
    float offset = 0.0f;

    float e[8], f[8];
#pragma unroll
    for (int r = 0; r < 8; ++r) e[r] = bfeats[r * CRF_K];

    // uniform-index bpermute broadcast: all lanes pull lane j's P (VGPR dest,
    // DS pipe, no SGPR-write hazard).
    auto bp = [&](int Pi, int j) -> float {
      return __int_as_float(__builtin_amdgcn_ds_bpermute(zosrc + 4 * j, Pi));
    };

    // one step: P' = (E . P) * exp(emit). Column STOP of E is exactly 0 ->
    // skip j=63. 63 bpermutes all depend only on P (issue back-to-back,
    // pipelined on the DS pipe); 4 independent FMA chains consume them.
    auto do_step = [&](float ee) {
      const int Pi = __float_as_int(P);
      float a0 = 0.f, a1 = 0.f, a2 = 0.f, a3 = 0.f;
#pragma unroll
      for (int j = 0; j < 16; ++j) a0 = __builtin_fmaf(E0[j], bp(Pi, j), a0);
#pragma unroll
      for (int j = 0; j < 16; ++j) a1 = __builtin_fmaf(E1[j], bp(Pi, 16 + j), a1);
#pragma unroll
      for (int j = 0; j < 16; ++j) a2 = __builtin_fmaf(E2[j], bp(Pi, 32 + j), a2);
#pragma unroll
      for (int j = 0; j < 15; ++j) a3 = __builtin_fmaf(E3[j], bp(Pi, 48 + j), a3);
      P = ((a0 + a1) + (a2 + a3)) * ee;
    };

    // wave-uniform rescale by lane 0's P (LSE identity holds for ANY finite
    // normalizer; P[0] > 0 after step 1 since only row START of E is all-zero).
    // Once per 8 steps -> readlane cost here is negligible.
    auto rescale = [&](int first) {
      float M = first ? 1.0f
                      : __int_as_float(
                            __builtin_amdgcn_readlane(__float_as_int(P), 0));
      offset += __logf(M);
      P *= __builtin_amdgcn_rcpf(M);
    };

    const int Lb = L & ~7;
    for (int t0 = 0; t0 < Lb; t0 += 8) {
      const int tn = t0 + 8;
      if (tn < CRF_T) {  // prefetch next 8-step block (wave-uniform branch)
#pragma unroll
        for (int r = 0; r < 8; ++r) f[r] = bfeats[(tn + r) * CRF_K];
      } else {
#pragma unroll
        for (int r = 0; r < 8; ++r) f[r] = 0.0f;
      }
      float ee[8];
#pragma unroll
      for (int r = 0; r < 8; ++r) ee[r] = __expf(e[r]);  // off-chain, hides

      rescale(t0 == 0);  // growth over 8 steps ~e^64 < f32 max (R2 verified)

#pragma unroll
      for (int r = 0; r < 8; ++r) do_step(ee[r]);
#pragma unroll
      for (int r = 0; r < 8; ++r) e[r] = f[r];
    }

    // tail (<= 7 steps)
    if (Lb < L) {
      rescale(Lb == 0);
#pragma unroll
      for (int r = 0; r < 8; ++r) {
        if (Lb + r < L) do_step(__expf(e[r]));
      }
    }

    // terminal: fwd = offset + log( sum_i P[i] * exp(trans[STOP][i]) )
    float eST = __expf(sT[CRF_STOP * 65 + lane]);  // exp(-10000)=0 kills i=STOP
    float v = P * eST;
    float s2 = wave_sum64(v);
    float fwd = offset + __logf(s2);
    if (lane == 0) atomicAdd(out, fwd * (1.0f / CRF_B));
  } else {
    // ---------------- gold wave (fully parallel) ----------------
    const int* btags = tags + b * CRF_T;
    const float* bf = feats + (size_t)b * CRF_T * CRF_K;
    float gold = 0.0f;
#pragma unroll
    for (int base = 0; base < CRF_T; base += 64) {
      int t = base + lane;
      if (t < L) {
        int tg = btags[t];
        int tp = (t == 0) ? CRF_START : btags[t - 1];
        gold += bf[(size_t)t * CRF_K + tg];   // emit score
        gold += sT[tg * 65 + tp];             // transition score
      }
    }
    gold = wave_sum64(gold);
    if (lane == 0) {
      gold += sT[CRF_STOP * 65 + btags[L - 1]];  // terminal transition
      atomicAdd(out, -gold * (1.0f / CRF_B));
    }
  }
}

extern "C" void kernel_launch(void* const* d_in, const int* in_sizes, int n_in,
                              void* d_out, int out_size, void* d_ws, size_t ws_size,
                              hipStream_t stream) {
  const float* feats = (const float*)d_in[0];
  const int* lengths = (const int*)d_in[1];
  const int* tags = (const int*)d_in[2];
  const float* trans = (const float*)d_in[3];
  float* out = (float*)d_out;
  hipMemsetAsync(out, 0, sizeof(float), stream);
  crf_kernel<<<CRF_B, 128, 0, stream>>>(feats, lengths, tags, trans, out);
}

// Round 14
// 419.940 us; speedup vs baseline: 1.1383x; 1.1383x over previous
//
#include <hip/hip_runtime.h>

#define CRF_B 1024
#define CRF_T 512
#define CRF_K 64
#define CRF_START 62
#define CRF_STOP 63

typedef float vf16 __attribute__((ext_vector_type(16)));

__device__ __forceinline__ float wave_sum64(float v) {
#pragma unroll
  for (int off = 32; off > 0; off >>= 1) v += __shfl_xor(v, off, 64);
  return v;
}

// wave rotate-right by 1 on the VALU pipe: lane l receives lane (l-1)&63.
// (LLVM AMDGPUAtomicOptimizer scan + GPUOpen cross-lane doc: row_shr:1 /
// wave_ror:1 bring data FROM the lower lane.) DPP_CTRL 0x13C = WAVE_ROR:1.
__device__ __forceinline__ float ror1(float x) {
  return __int_as_float(__builtin_amdgcn_update_dpp(
      __float_as_int(x), __float_as_int(x), 0x13C, 0xF, 0xF, false));
}

// R7 (second resubmit, unmeasured due to GPU acquisition timeouts):
// systolic rotation replaces ALL per-step lane broadcasts.
// Evidence trail: R0/R5 (63 v_readlane/step) ~715cy/step -> readlane ~8cy
// throughput wall on the VGPR->SGPR path. R6 (ds_bpermute) REGRESSED to
// ~1663cy/step, VALUBusy 5.4%: DS-pipe latency (~26cy effective) cannot be
// hidden with 1 wave/SIMD and a serial P->broadcast->FMA->P recurrence.
// Law: the broadcast must live on the VALU pipe with forwarding.
// Fix: store E rows ROTATED (Erot[k] = E[l][(l-k)&63], one-time LDS loads at
// setup) and rotate a copy of P by wave_ror:1 each term:
//   P'[l] = sum_k Erot[k] * P[(l-k)&63]  == (E.P)[l]
// 63 v_mov_dpp + 64 v_fma per step, all VALU: ~254 issue-cy, ~252cy dep
// chain -> ~260-320cy/step vs R5's 715.
__global__ __launch_bounds__(128, 1) void crf_kernel(
    const float* __restrict__ feats, const int* __restrict__ lengths,
    const int* __restrict__ tags, const float* __restrict__ trans,
    float* __restrict__ out) {
  // padded stride 65: conflict-free row reads, cheap random reads for gold wave
  __shared__ float sT[CRF_K * 65];

  const int b = blockIdx.x;
  const int tid = threadIdx.x;
  const int lane = tid & 63;

  for (int idx = tid; idx < CRF_K * CRF_K; idx += 128)
    sT[(idx >> 6) * 65 + (idx & 63)] = trans[idx];
  __syncthreads();

  const int L = lengths[b];

  if (tid < 64) {
    // ---------------- forward wave (exp domain) ----------------
    // lane l holds its E row ROTATED: E0..E3[k] = exp(trans[l][(l-K)&63]),
    // K = global rotation count 0..63. Four ext-vector SSA values,
    // constant-index extracts only (R3-proven VGPR-resident pattern; R5's
    // select-lambda demoted E to scratch - avoided here).
    vf16 E0, E1, E2, E3;
    {
      const float* trow = &sT[lane * 65];
#pragma unroll
      for (int k = 0; k < 16; ++k) E0[k] = __expf(trow[(lane - k) & 63]);
#pragma unroll
      for (int k = 0; k < 16; ++k) E1[k] = __expf(trow[(lane - 16 - k) & 63]);
#pragma unroll
      for (int k = 0; k < 16; ++k) E2[k] = __expf(trow[(lane - 32 - k) & 63]);
#pragma unroll
      for (int k = 0; k < 16; ++k) E3[k] = __expf(trow[(lane - 48 - k) & 63]);
    }

    const float* bfeats = feats + (size_t)b * CRF_T * CRF_K + lane;

    // P[i] = exp(alpha[i] - offset); alpha0 = delta_START
    float P = (lane == CRF_START) ? 1.0f : 0.0f;
    float offset = 0.0f;

    float e[8], f[8];
#pragma unroll
    for (int r = 0; r < 8; ++r) e[r] = bfeats[r * CRF_K];

    // one step: P' = (E . P) * exp(emit). The j=STOP column of E is zero and
    // lands at lane-dependent k, so all 64 terms are computed (one is a
    // harmless zero-FMA). 63 dpp rotations thread through 4 FMA chains.
    auto do_step = [&](float ee) {
      float pr = P;
      float a0 = E0[0] * pr;  // k=0: diagonal term, unrotated
      float a1 = 0.f, a2 = 0.f, a3 = 0.f;
#pragma unroll
      for (int k = 1; k < 16; ++k) {
        pr = ror1(pr);
        a0 = __builtin_fmaf(E0[k], pr, a0);
      }
#pragma unroll
      for (int k = 0; k < 16; ++k) {
        pr = ror1(pr);
        a1 = __builtin_fmaf(E1[k], pr, a1);
      }
#pragma unroll
      for (int k = 0; k < 16; ++k) {
        pr = ror1(pr);
        a2 = __builtin_fmaf(E2[k], pr, a2);
      }
#pragma unroll
      for (int k = 0; k < 16; ++k) {
        pr = ror1(pr);
        a3 = __builtin_fmaf(E3[k], pr, a3);
      }
      P = ((a0 + a1) + (a2 + a3)) * ee;
    };

    // wave-uniform rescale by lane 0's P (LSE identity holds for ANY finite
    // normalizer; P[0] > 0 after step 1 since only row START of E is
    // all-zero). Once per 8 steps -> readlane cost here is negligible.
    auto rescale = [&](int first) {
      float M = first ? 1.0f
                      : __int_as_float(
                            __builtin_amdgcn_readlane(__float_as_int(P), 0));
      offset += __logf(M);
      P *= __builtin_amdgcn_rcpf(M);
    };

    const int Lb = L & ~7;
    for (int t0 = 0; t0 < Lb; t0 += 8) {
      const int tn = t0 + 8;
      if (tn < CRF_T) {  // prefetch next 8-step block (wave-uniform branch)
#pragma unroll
        for (int r = 0; r < 8; ++r) f[r] = bfeats[(tn + r) * CRF_K];
      } else {
#pragma unroll
        for (int r = 0; r < 8; ++r) f[r] = 0.0f;
      }
      float ee[8];
#pragma unroll
      for (int r = 0; r < 8; ++r) ee[r] = __expf(e[r]);  // off-chain, hides

      rescale(t0 == 0);  // growth over 8 steps ~e^64 < f32 max (R2 verified)

#pragma unroll
      for (int r = 0; r < 8; ++r) do_step(ee[r]);
#pragma unroll
      for (int r = 0; r < 8; ++r) e[r] = f[r];
    }

    // tail (<= 7 steps)
    if (Lb < L) {
      rescale(Lb == 0);
#pragma unroll
      for (int r = 0; r < 8; ++r) {
        if (Lb + r < L) do_step(__expf(e[r]));
      }
    }

    // terminal: fwd = offset + log( sum_i P[i] * exp(trans[STOP][i]) )
    float eST = __expf(sT[CRF_STOP * 65 + lane]);  // exp(-10000)=0 kills i=STOP
    float v = P * eST;
    float s2 = wave_sum64(v);
    float fwd = offset + __logf(s2);
    if (lane == 0) atomicAdd(out, fwd * (1.0f / CRF_B));
  } else {
    // ---------------- gold wave (fully parallel) ----------------
    const int* btags = tags + b * CRF_T;
    const float* bf = feats + (size_t)b * CRF_T * CRF_K;
    float gold = 0.0f;
#pragma unroll
    for (int base = 0; base < CRF_T; base += 64) {
      int t = base + lane;
      if (t < L) {
        int tg = btags[t];
        int tp = (t == 0) ? CRF_START : btags[t - 1];
        gold += bf[(size_t)t * CRF_K + tg];   // emit score
        gold += sT[tg * 65 + tp];             // transition score
      }
    }
    gold = wave_sum64(gold);
    if (lane == 0) {
      gold += sT[CRF_STOP * 65 + btags[L - 1]];  // terminal transition
      atomicAdd(out, -gold * (1.0f / CRF_B));
    }
  }
}

extern "C" void kernel_launch(void* const* d_in, const int* in_sizes, int n_in,
                              void* d_out, int out_size, void* d_ws, size_t ws_size,
                              hipStream_t stream) {
  const float* feats = (const float*)d_in[0];
  const int* lengths = (const int*)d_in[1];
  const int* tags = (const int*)d_in[2];
  const float* trans = (const float*)d_in[3];
  float* out = (float*)d_out;
  hipMemsetAsync(out, 0, sizeof(float), stream);
  crf_kernel<<<CRF_B, 128, 0, stream>>>(feats, lengths, tags, trans, out);
}

// Round 16
// 359.988 us; speedup vs baseline: 1.3278x; 1.1665x over previous
//
#include <hip/hip_runtime.h>

#define CRF_B 1024
#define CRF_T 512
#define CRF_K 64
#define CRF_START 62
#define CRF_STOP 63

typedef float vf16 __attribute__((ext_vector_type(16)));

__device__ __forceinline__ float wave_sum64(float v) {
#pragma unroll
  for (int off = 32; off > 0; off >>= 1) v += __shfl_xor(v, off, 64);
  return v;
}

// row_ror:S — rotate right by S within each 16-lane row, VALU pipe, and all
// uses below are INDEPENDENT (each reads a loop-invariant base register).
// DPP_CTRL = 0x120 + S. Same direction convention as R7's wave_ror:1
// (absmax=0 verified): lane l receives (rowbase)+((l-S)&15).
#define ROR(x, S)                                                         \
  __int_as_float(__builtin_amdgcn_update_dpp(                             \
      __float_as_int(x), __float_as_int(x), 0x120 + (S), 0xF, 0xF, false))

// 16-term block: acc = sum_s Ev[s] * row_ror:s(base). 15 independent DPPs +
// 16 FMAs; single accumulator chain (4 chains overlap across blocks).
#define BLOCK16(acc, Ev, base)                                  \
  do {                                                          \
    acc = Ev[0] * (base);                                       \
    acc = __builtin_fmaf(Ev[1], ROR(base, 1), acc);             \
    acc = __builtin_fmaf(Ev[2], ROR(base, 2), acc);             \
    acc = __builtin_fmaf(Ev[3], ROR(base, 3), acc);             \
    acc = __builtin_fmaf(Ev[4], ROR(base, 4), acc);             \
    acc = __builtin_fmaf(Ev[5], ROR(base, 5), acc);             \
    acc = __builtin_fmaf(Ev[6], ROR(base, 6), acc);             \
    acc = __builtin_fmaf(Ev[7], ROR(base, 7), acc);             \
    acc = __builtin_fmaf(Ev[8], ROR(base, 8), acc);             \
    acc = __builtin_fmaf(Ev[9], ROR(base, 9), acc);             \
    acc = __builtin_fmaf(Ev[10], ROR(base, 10), acc);           \
    acc = __builtin_fmaf(Ev[11], ROR(base, 11), acc);           \
    acc = __builtin_fmaf(Ev[12], ROR(base, 12), acc);           \
    acc = __builtin_fmaf(Ev[13], ROR(base, 13), acc);           \
    acc = __builtin_fmaf(Ev[14], ROR(base, 14), acc);           \
    acc = __builtin_fmaf(Ev[15], ROR(base, 15), acc);           \
  } while (0)

// R8 (resubmit, unmeasured last round): block-rotation systolic.
// Evidence trail:
//  R0/R5 (63 serial v_readlane/step): ~715cy/step - SGPR-path throughput wall.
//  R6 (63 ds_bpermute/step): ~1663cy/step - DS latency unhidable, 1 wave/SIMD.
//  R7 (63 SERIAL-DEPENDENT wave_ror:1/step): ~1300cy/step - dependent DPP
//    latency ~15-20cy/link; VALUBusy 26% (issue 340cy, stall 960cy).
// Law: cross-lane ops only help when INDEPENDENT. R8 makes them so:
//  P'[l] = sum_{m=0..3} sum_{s=0..15} E_m[s][l] * row_ror:s(C_m)[l],
//  C_m[l] = P[l^(16m)] via 3 INDEPENDENT ds_bpermute (latency hides under
//  the m=0 FMA block); 60 INDEPENDENT row_ror DPPs (pipelined).
// ~130 instr/step ~ 270 issue-cy, dep path ~100cy -> predict ~300-360cy/step.
__global__ __launch_bounds__(128, 1) void crf_kernel(
    const float* __restrict__ feats, const int* __restrict__ lengths,
    const int* __restrict__ tags, const float* __restrict__ trans,
    float* __restrict__ out) {
  // padded stride 65: conflict-free row reads, cheap random reads for gold wave
  __shared__ float sT[CRF_K * 65];

  const int b = blockIdx.x;
  const int tid = threadIdx.x;
  const int lane = tid & 63;

  for (int idx = tid; idx < CRF_K * CRF_K; idx += 128)
    sT[(idx >> 6) * 65 + (idx & 63)] = trans[idx];
  __syncthreads();

  const int L = lengths[b];

  if (tid < 64) {
    // ---------------- forward wave (exp domain) ----------------
    // E pre-shuffled for the block-rotation identity:
    //   E_m[s][l] = exp(trans[l][ 16*((l>>4)^m) + ((l-s)&15) ])
    // so that term (m,s) multiplies row_ror:s(C_m). Four ext-vector SSA
    // values, constant-index extracts only (R3-proven resident pattern).
    vf16 E0, E1, E2, E3;
    {
      const float* trow = &sT[lane * 65];
      const int r16 = lane & 48;  // 16*(lane>>4)
#pragma unroll
      for (int s = 0; s < 16; ++s) E0[s] = __expf(trow[r16 + ((lane - s) & 15)]);
#pragma unroll
      for (int s = 0; s < 16; ++s) E1[s] = __expf(trow[(r16 ^ 16) + ((lane - s) & 15)]);
#pragma unroll
      for (int s = 0; s < 16; ++s) E2[s] = __expf(trow[(r16 ^ 32) + ((lane - s) & 15)]);
#pragma unroll
      for (int s = 0; s < 16; ++s) E3[s] = __expf(trow[(r16 ^ 48) + ((lane - s) & 15)]);
    }

    // precomputed bpermute byte-addresses for the 3 cross-row pulls
    const int a16 = (lane ^ 16) << 2;
    const int a32 = (lane ^ 32) << 2;
    const int a48 = (lane ^ 48) << 2;

    const float* bfeats = feats + (size_t)b * CRF_T * CRF_K + lane;

    // P[i] = exp(alpha[i] - offset); alpha0 = delta_START
    float P = (lane == CRF_START) ? 1.0f : 0.0f;
    float offset = 0.0f;

    float e[8], f[8];
#pragma unroll
    for (int r = 0; r < 8; ++r) e[r] = bfeats[r * CRF_K];

    // one step: P' = (E . P) * exp(emit). STOP column of E is 0 (harmless
    // zero-FMA at a lane-dependent (m,s)).
    auto do_step = [&](float ee) {
      const int Pi = __float_as_int(P);
      // 3 independent cross-row pulls, issued first; latency hides under
      // the m=0 block (no dependency on them).
      float C1 = __int_as_float(__builtin_amdgcn_ds_bpermute(a16, Pi));
      float C2 = __int_as_float(__builtin_amdgcn_ds_bpermute(a32, Pi));
      float C3 = __int_as_float(__builtin_amdgcn_ds_bpermute(a48, Pi));
      float a0, a1, a2, a3;
      BLOCK16(a0, E0, P);
      BLOCK16(a1, E1, C1);
      BLOCK16(a2, E2, C2);
      BLOCK16(a3, E3, C3);
      P = ((a0 + a1) + (a2 + a3)) * ee;
    };

    // wave-uniform rescale by lane 0's P (LSE identity holds for ANY finite
    // normalizer; P[0] > 0 after step 1 since only row START of E is
    // all-zero). Once per 8 steps -> readlane cost negligible.
    auto rescale = [&](int first) {
      float M = first ? 1.0f
                      : __int_as_float(
                            __builtin_amdgcn_readlane(__float_as_int(P), 0));
      offset += __logf(M);
      P *= __builtin_amdgcn_rcpf(M);
    };

    const int Lb = L & ~7;
    for (int t0 = 0; t0 < Lb; t0 += 8) {
      const int tn = t0 + 8;
      if (tn < CRF_T) {  // prefetch next 8-step block (wave-uniform branch)
#pragma unroll
        for (int r = 0; r < 8; ++r) f[r] = bfeats[(tn + r) * CRF_K];
      } else {
#pragma unroll
        for (int r = 0; r < 8; ++r) f[r] = 0.0f;
      }
      float ee[8];
#pragma unroll
      for (int r = 0; r < 8; ++r) ee[r] = __expf(e[r]);  // off-chain, hides

      rescale(t0 == 0);  // growth over 8 steps ~e^64 < f32 max (R2 verified)

#pragma unroll
      for (int r = 0; r < 8; ++r) do_step(ee[r]);
#pragma unroll
      for (int r = 0; r < 8; ++r) e[r] = f[r];
    }

    // tail (<= 7 steps)
    if (Lb < L) {
      rescale(Lb == 0);
#pragma unroll
      for (int r = 0; r < 8; ++r) {
        if (Lb + r < L) do_step(__expf(e[r]));
      }
    }

    // terminal: fwd = offset + log( sum_i P[i] * exp(trans[STOP][i]) )
    float eST = __expf(sT[CRF_STOP * 65 + lane]);  // exp(-10000)=0 kills i=STOP
    float v = P * eST;
    float s2 = wave_sum64(v);
    float fwd = offset + __logf(s2);
    if (lane == 0) atomicAdd(out, fwd * (1.0f / CRF_B));
  } else {
    // ---------------- gold wave (fully parallel) ----------------
    const int* btags = tags + b * CRF_T;
    const float* bf = feats + (size_t)b * CRF_T * CRF_K;
    float gold = 0.0f;
#pragma unroll
    for (int base = 0; base < CRF_T; base += 64) {
      int t = base + lane;
      if (t < L) {
        int tg = btags[t];
        int tp = (t == 0) ? CRF_START : btags[t - 1];
        gold += bf[(size_t)t * CRF_K + tg];   // emit score
        gold += sT[tg * 65 + tp];             // transition score
      }
    }
    gold = wave_sum64(gold);
    if (lane == 0) {
      gold += sT[CRF_STOP * 65 + btags[L - 1]];  // terminal transition
      atomicAdd(out, -gold * (1.0f / CRF_B));
    }
  }
}

extern "C" void kernel_launch(void* const* d_in, const int* in_sizes, int n_in,
                              void* d_out, int out_size, void* d_ws, size_t ws_size,
                              hipStream_t stream) {
  const float* feats = (const float*)d_in[0];
  const int* lengths = (const int*)d_in[1];
  const int* tags = (const int*)d_in[2];
  const float* trans = (const float*)d_in[3];
  float* out = (float*)d_out;
  hipMemsetAsync(out, 0, sizeof(float), stream);
  crf_kernel<<<CRF_B, 128, 0, stream>>>(feats, lengths, tags, trans, out);
}